// Round 1
// baseline (2930.391 us; speedup 1.0000x reference)
//
#include <hip/hip_runtime.h>

#define IN_F 256
#define OUT_F 128
#define ROWS_PER_ITER 16

// ---------------- Kernel A: x = (input * drop_mask) @ W ----------------
// Block: 256 threads. W (256x128 f32 = 128 KB) staged in LDS once per block.
// Each iter: stage 16 rows of (input*mask) in LDS, each thread computes
// 2 rows x 4 cols with float4 W reads.
__global__ __launch_bounds__(256, 1)
void gemm_dropout_kernel(const float* __restrict__ in,
                         const float* __restrict__ mask,
                         const float* __restrict__ W,
                         float* __restrict__ x, int N) {
    __shared__ float Wlds[IN_F * OUT_F];        // 128 KB
    __shared__ float rbuf[ROWS_PER_ITER][IN_F]; // 16 KB
    const int tid = threadIdx.x;

    // Stage W into LDS (coalesced float4)
    const float4* W4 = (const float4*)W;
    float4* Wl4 = (float4*)Wlds;
    for (int i = tid; i < IN_F * OUT_F / 4; i += 256) Wl4[i] = W4[i];

    const int cg = tid & 31;   // column group: 4 consecutive cols
    const int rp = tid >> 5;   // row pair index 0..7

    for (int base = blockIdx.x * ROWS_PER_ITER; base < N;
         base += gridDim.x * ROWS_PER_ITER) {
        __syncthreads();  // protect rbuf (and W on first iter)
        // Stage 16 rows of input*mask: 16*256/4 = 1024 float4 / 256 thr
        for (int i = tid; i < ROWS_PER_ITER * IN_F / 4; i += 256) {
            int r = i >> 6;           // /(IN_F/4)
            int cc = i & 63;
            int grow = base + r;
            float4 p = {0.f, 0.f, 0.f, 0.f};
            if (grow < N) {
                float4 a = ((const float4*)(in + (size_t)grow * IN_F))[cc];
                float4 m = ((const float4*)(mask + (size_t)grow * IN_F))[cc];
                p.x = a.x * m.x; p.y = a.y * m.y;
                p.z = a.z * m.z; p.w = a.w * m.w;
            }
            ((float4*)rbuf)[i] = p;
        }
        __syncthreads();

        float4 acc0 = {0.f, 0.f, 0.f, 0.f};
        float4 acc1 = {0.f, 0.f, 0.f, 0.f};
        const float4* Wl4c = (const float4*)Wlds;
        const int r0l = rp * 2, r1l = rp * 2 + 1;
#pragma unroll 4
        for (int k = 0; k < IN_F; ++k) {
            float4 w = Wl4c[k * 32 + cg];
            float xv0 = rbuf[r0l][k];
            float xv1 = rbuf[r1l][k];
            acc0.x += w.x * xv0; acc0.y += w.y * xv0;
            acc0.z += w.z * xv0; acc0.w += w.w * xv0;
            acc1.x += w.x * xv1; acc1.y += w.y * xv1;
            acc1.z += w.z * xv1; acc1.w += w.w * xv1;
        }
        int gr0 = base + r0l, gr1 = base + r1l;
        if (gr0 < N) ((float4*)(x + (size_t)gr0 * OUT_F))[cg] = acc0;
        if (gr1 < N) ((float4*)(x + (size_t)gr1 * OUT_F))[cg] = acc1;
    }
}

// ---------------- Kernel B: edge scatter with atomics ----------------
// 32 lanes per edge, each lane handles 4 consecutive floats (float4 gather,
// 4x atomicAdd scatter).
__global__ __launch_bounds__(256)
void edge_scatter_kernel(const float* __restrict__ x,
                         const float* __restrict__ adj_val,
                         const int* __restrict__ edge_row,
                         const int* __restrict__ edge_col,
                         float* __restrict__ out, int E) {
    long long idx = (long long)blockIdx.x * blockDim.x + threadIdx.x;
    int e = (int)(idx >> 5);
    int sub = (int)(idx & 31);
    if (e >= E) return;
    int r = edge_row[e];
    int c = edge_col[e];
    float v = adj_val[e];
    float4 xv = ((const float4*)x)[(size_t)c * 32 + sub];
    float* dst = out + (size_t)r * OUT_F + sub * 4;
    atomicAdd(dst + 0, v * xv.x);
    atomicAdd(dst + 1, v * xv.y);
    atomicAdd(dst + 2, v * xv.z);
    atomicAdd(dst + 3, v * xv.w);
}

// ---------------- Kernel C: ReLU ----------------
__global__ __launch_bounds__(256)
void relu_kernel(float* __restrict__ out, int n4) {
    int stride = gridDim.x * blockDim.x;
    for (int i = blockIdx.x * blockDim.x + threadIdx.x; i < n4; i += stride) {
        float4 v = ((float4*)out)[i];
        v.x = fmaxf(v.x, 0.f); v.y = fmaxf(v.y, 0.f);
        v.z = fmaxf(v.z, 0.f); v.w = fmaxf(v.w, 0.f);
        ((float4*)out)[i] = v;
    }
}

extern "C" void kernel_launch(void* const* d_in, const int* in_sizes, int n_in,
                              void* d_out, int out_size, void* d_ws, size_t ws_size,
                              hipStream_t stream) {
    const float* input    = (const float*)d_in[0];
    const float* weight   = (const float*)d_in[1];
    const float* adj_val  = (const float*)d_in[2];
    const float* drop_mask= (const float*)d_in[3];
    const int*   edge_row = (const int*)d_in[4];
    const int*   edge_col = (const int*)d_in[5];
    float* out = (float*)d_out;

    const int N = in_sizes[0] / IN_F;     // 100000
    const int E = in_sizes[2];            // 1600000

    float* x = (float*)d_ws;              // N * OUT_F floats = 51.2 MB

    // Phase 1: fused dropout + GEMM
    gemm_dropout_kernel<<<256, 256, 0, stream>>>(input, drop_mask, weight, x, N);

    // Zero output accumulator
    hipMemsetAsync(d_out, 0, (size_t)out_size * sizeof(float), stream);

    // Phase 2: edge scatter
    long long threads = (long long)E * 32;
    int blocks = (int)((threads + 255) / 256);
    edge_scatter_kernel<<<blocks, 256, 0, stream>>>(x, adj_val, edge_row,
                                                    edge_col, out, E);

    // Phase 3: ReLU
    relu_kernel<<<2048, 256, 0, stream>>>(out, out_size / 4);
}

// Round 2
// 521.650 us; speedup vs baseline: 5.6175x; 5.6175x over previous
//
#include <hip/hip_runtime.h>

#define IN_F 256
#define OUT_F 128
#define ROWS_PER_ITER 16
#define CHUNK 1024

// ---------------- Kernel A: x = (input * drop_mask) @ W ----------------
__global__ __launch_bounds__(256, 1)
void gemm_dropout_kernel(const float* __restrict__ in,
                         const float* __restrict__ mask,
                         const float* __restrict__ W,
                         float* __restrict__ x, int N) {
    __shared__ float Wlds[IN_F * OUT_F];        // 128 KB
    __shared__ float rbuf[ROWS_PER_ITER][IN_F]; // 16 KB
    const int tid = threadIdx.x;

    const float4* W4 = (const float4*)W;
    float4* Wl4 = (float4*)Wlds;
    for (int i = tid; i < IN_F * OUT_F / 4; i += 256) Wl4[i] = W4[i];

    const int cg = tid & 31;
    const int rp = tid >> 5;

    for (int base = blockIdx.x * ROWS_PER_ITER; base < N;
         base += gridDim.x * ROWS_PER_ITER) {
        __syncthreads();
        for (int i = tid; i < ROWS_PER_ITER * IN_F / 4; i += 256) {
            int r = i >> 6;
            int cc = i & 63;
            int grow = base + r;
            float4 p = {0.f, 0.f, 0.f, 0.f};
            if (grow < N) {
                float4 a = ((const float4*)(in + (size_t)grow * IN_F))[cc];
                float4 m = ((const float4*)(mask + (size_t)grow * IN_F))[cc];
                p.x = a.x * m.x; p.y = a.y * m.y;
                p.z = a.z * m.z; p.w = a.w * m.w;
            }
            ((float4*)rbuf)[i] = p;
        }
        __syncthreads();

        float4 acc0 = {0.f, 0.f, 0.f, 0.f};
        float4 acc1 = {0.f, 0.f, 0.f, 0.f};
        const float4* Wl4c = (const float4*)Wlds;
        const int r0l = rp * 2, r1l = rp * 2 + 1;
#pragma unroll 4
        for (int k = 0; k < IN_F; ++k) {
            float4 w = Wl4c[k * 32 + cg];
            float xv0 = rbuf[r0l][k];
            float xv1 = rbuf[r1l][k];
            acc0.x += w.x * xv0; acc0.y += w.y * xv0;
            acc0.z += w.z * xv0; acc0.w += w.w * xv0;
            acc1.x += w.x * xv1; acc1.y += w.y * xv1;
            acc1.z += w.z * xv1; acc1.w += w.w * xv1;
        }
        int gr0 = base + r0l, gr1 = base + r1l;
        if (gr0 < N) ((float4*)(x + (size_t)gr0 * OUT_F))[cg] = acc0;
        if (gr1 < N) ((float4*)(x + (size_t)gr1 * OUT_F))[cg] = acc1;
    }
}

// ---------------- CSR build ----------------
__global__ __launch_bounds__(256)
void count_kernel(const int* __restrict__ edge_row, int* __restrict__ count,
                  int E) {
    int e = blockIdx.x * blockDim.x + threadIdx.x;
    if (e < E) atomicAdd(&count[edge_row[e]], 1);
}

// partial[chunk] = sum of count[chunk*CHUNK .. +CHUNK)
__global__ __launch_bounds__(256)
void chunk_sums_kernel(const int* __restrict__ count, int* __restrict__ partial,
                       int N) {
    __shared__ int s[256];
    int tid = threadIdx.x;
    int base = blockIdx.x * CHUNK + tid * 4;
    int sum = 0;
#pragma unroll
    for (int j = 0; j < 4; ++j) {
        int i = base + j;
        if (i < N) sum += count[i];
    }
    s[tid] = sum;
    __syncthreads();
    for (int d = 128; d > 0; d >>= 1) {
        if (tid < d) s[tid] += s[tid + d];
        __syncthreads();
    }
    if (tid == 0) partial[blockIdx.x] = s[0];
}

// exclusive scan of partial[nchunks] -> chunk_off (serial, tiny)
__global__ void scan_chunks_kernel(const int* __restrict__ partial,
                                   int* __restrict__ chunk_off, int nchunks) {
    if (threadIdx.x == 0 && blockIdx.x == 0) {
        int acc = 0;
        for (int i = 0; i < nchunks; ++i) {
            chunk_off[i] = acc;
            acc += partial[i];
        }
    }
}

// per-chunk exclusive scan + chunk offset -> row_start, cursor
__global__ __launch_bounds__(256)
void chunk_scan_apply_kernel(const int* __restrict__ count,
                             const int* __restrict__ chunk_off,
                             int* __restrict__ row_start,
                             int* __restrict__ cursor, int N, int E) {
    __shared__ int s[256];
    int tid = threadIdx.x;
    int base = blockIdx.x * CHUNK + tid * 4;
    int c[4];
    int tsum = 0;
#pragma unroll
    for (int j = 0; j < 4; ++j) {
        int i = base + j;
        c[j] = (i < N) ? count[i] : 0;
        tsum += c[j];
    }
    s[tid] = tsum;
    __syncthreads();
    for (int d = 1; d < 256; d <<= 1) {
        int v = (tid >= d) ? s[tid - d] : 0;
        __syncthreads();
        s[tid] += v;
        __syncthreads();
    }
    int pre = chunk_off[blockIdx.x] + s[tid] - tsum;
#pragma unroll
    for (int j = 0; j < 4; ++j) {
        int i = base + j;
        if (i < N) { row_start[i] = pre; cursor[i] = pre; }
        pre += c[j];
    }
    if (blockIdx.x == 0 && tid == 0) row_start[N] = E;
}

// scatter edges into CSR slots: cv[pos] = (col, val)
__global__ __launch_bounds__(256)
void csr_scatter_kernel(const int* __restrict__ edge_row,
                        const int* __restrict__ edge_col,
                        const float* __restrict__ adj_val,
                        int* __restrict__ cursor, int2* __restrict__ cv,
                        int E) {
    int e = blockIdx.x * blockDim.x + threadIdx.x;
    if (e >= E) return;
    int r = edge_row[e];
    int pos = atomicAdd(&cursor[r], 1);
    int2 p;
    p.x = edge_col[e];
    p.y = __float_as_int(adj_val[e]);
    cv[pos] = p;
}

// ---------------- per-node gather + accumulate + ReLU ----------------
__global__ __launch_bounds__(256)
void gather_accum_kernel(const float* __restrict__ x,
                         const int2* __restrict__ cv,
                         const int* __restrict__ row_start,
                         float* __restrict__ out, int N) {
    int g = (blockIdx.x * blockDim.x + threadIdx.x) >> 5;  // node
    int lane = threadIdx.x & 31;
    if (g >= N) return;
    int s = row_start[g];
    int e1 = row_start[g + 1];
    float4 acc = {0.f, 0.f, 0.f, 0.f};
    for (int e = s; e < e1; ++e) {
        int2 p = cv[e];
        float v = __int_as_float(p.y);
        float4 xv = ((const float4*)x)[(size_t)p.x * 32 + lane];
        acc.x += v * xv.x; acc.y += v * xv.y;
        acc.z += v * xv.z; acc.w += v * xv.w;
    }
    acc.x = fmaxf(acc.x, 0.f); acc.y = fmaxf(acc.y, 0.f);
    acc.z = fmaxf(acc.z, 0.f); acc.w = fmaxf(acc.w, 0.f);
    ((float4*)(out + (size_t)g * OUT_F))[lane] = acc;
}

// ---------------- fallback (atomic path, round-1) ----------------
__global__ __launch_bounds__(256)
void edge_scatter_kernel(const float* __restrict__ x,
                         const float* __restrict__ adj_val,
                         const int* __restrict__ edge_row,
                         const int* __restrict__ edge_col,
                         float* __restrict__ out, int E) {
    long long idx = (long long)blockIdx.x * blockDim.x + threadIdx.x;
    int e = (int)(idx >> 5);
    int sub = (int)(idx & 31);
    if (e >= E) return;
    int r = edge_row[e];
    int c = edge_col[e];
    float v = adj_val[e];
    float4 xv = ((const float4*)x)[(size_t)c * 32 + sub];
    float* dst = out + (size_t)r * OUT_F + sub * 4;
    atomicAdd(dst + 0, v * xv.x);
    atomicAdd(dst + 1, v * xv.y);
    atomicAdd(dst + 2, v * xv.z);
    atomicAdd(dst + 3, v * xv.w);
}

__global__ __launch_bounds__(256)
void relu_kernel(float* __restrict__ out, int n4) {
    int stride = gridDim.x * blockDim.x;
    for (int i = blockIdx.x * blockDim.x + threadIdx.x; i < n4; i += stride) {
        float4 v = ((float4*)out)[i];
        v.x = fmaxf(v.x, 0.f); v.y = fmaxf(v.y, 0.f);
        v.z = fmaxf(v.z, 0.f); v.w = fmaxf(v.w, 0.f);
        ((float4*)out)[i] = v;
    }
}

static inline size_t align_up(size_t v, size_t a) { return (v + a - 1) & ~(a - 1); }

extern "C" void kernel_launch(void* const* d_in, const int* in_sizes, int n_in,
                              void* d_out, int out_size, void* d_ws, size_t ws_size,
                              hipStream_t stream) {
    const float* input     = (const float*)d_in[0];
    const float* weight    = (const float*)d_in[1];
    const float* adj_val   = (const float*)d_in[2];
    const float* drop_mask = (const float*)d_in[3];
    const int*   edge_row  = (const int*)d_in[4];
    const int*   edge_col  = (const int*)d_in[5];
    float* out = (float*)d_out;

    const int N = in_sizes[0] / IN_F;     // 100000
    const int E = in_sizes[2];            // 1600000
    const int nchunks = (N + CHUNK - 1) / CHUNK;

    // workspace layout
    char* ws = (char*)d_ws;
    size_t off = 0;
    float* x = (float*)(ws + off);           off = align_up(off + (size_t)N * OUT_F * 4, 256);
    int* count = (int*)(ws + off);           off = align_up(off + (size_t)N * 4, 256);
    int* row_start = (int*)(ws + off);       off = align_up(off + (size_t)(N + 1) * 4, 256);
    int* cursor = (int*)(ws + off);          off = align_up(off + (size_t)N * 4, 256);
    int* partial = (int*)(ws + off);         off = align_up(off + (size_t)nchunks * 4, 256);
    int* chunk_off = (int*)(ws + off);       off = align_up(off + (size_t)nchunks * 4, 256);
    int2* cv = (int2*)(ws + off);            off = align_up(off + (size_t)E * 8, 256);
    const bool have_ws = (off <= ws_size);

    // Phase 1: fused dropout + GEMM  (x in ws — requires at least x to fit)
    gemm_dropout_kernel<<<256, 256, 0, stream>>>(input, drop_mask, weight, x, N);

    if (have_ws) {
        // Phase 2: CSR build
        hipMemsetAsync(count, 0, (size_t)N * 4, stream);
        count_kernel<<<(E + 255) / 256, 256, 0, stream>>>(edge_row, count, E);
        chunk_sums_kernel<<<nchunks, 256, 0, stream>>>(count, partial, N);
        scan_chunks_kernel<<<1, 64, 0, stream>>>(partial, chunk_off, nchunks);
        chunk_scan_apply_kernel<<<nchunks, 256, 0, stream>>>(count, chunk_off,
                                                             row_start, cursor, N, E);
        csr_scatter_kernel<<<(E + 255) / 256, 256, 0, stream>>>(edge_row, edge_col,
                                                                adj_val, cursor, cv, E);
        // Phase 3: gather + accumulate + ReLU (writes every output element)
        gather_accum_kernel<<<(N * 32 + 255) / 256, 256, 0, stream>>>(x, cv,
                                                                      row_start, out, N);
    } else {
        // fallback: atomic scatter path
        hipMemsetAsync(d_out, 0, (size_t)out_size * sizeof(float), stream);
        long long threads = (long long)E * 32;
        int blocks = (int)((threads + 255) / 256);
        edge_scatter_kernel<<<blocks, 256, 0, stream>>>(x, adj_val, edge_row,
                                                        edge_col, out, E);
        relu_kernel<<<2048, 256, 0, stream>>>(out, out_size / 4);
    }
}

// Round 3
// 393.274 us; speedup vs baseline: 7.4513x; 1.3264x over previous
//
#include <hip/hip_runtime.h>

#define IN_F 256
#define OUT_F 128
#define ROWS_PER_ITER 32
#define GEMM_THREADS 512
#define CHUNK 1024

// ---------------- Kernel A: x = (input * drop_mask) @ W ----------------
// 512 threads (8 waves). W (128 KB) + rbuf (32 KB) = 160 KB LDS, 1 block/CU.
// Each thread: 2 rows x 4 cols. Register-prefetch next tile under compute.
__global__ __launch_bounds__(GEMM_THREADS, 1)
void gemm_dropout_kernel(const float* __restrict__ in,
                         const float* __restrict__ mask,
                         const float* __restrict__ W,
                         float* __restrict__ x, int N) {
    __shared__ float Wlds[IN_F * OUT_F];        // 128 KB
    __shared__ float rbuf[ROWS_PER_ITER][IN_F]; // 32 KB
    const int tid = threadIdx.x;

    // Stage W into LDS: 32768 floats / 512 thr = 16 float4 each
    {
        const float4* W4 = (const float4*)W;
        float4* Wl4 = (float4*)Wlds;
#pragma unroll
        for (int j = 0; j < 16; ++j) Wl4[tid + j * GEMM_THREADS] = W4[tid + j * GEMM_THREADS];
    }

    const int cg = tid & 31;          // 4-col group (cols cg*4..cg*4+3)
    const int rp = tid >> 5;          // 0..15 -> rows rp*2, rp*2+1

    // staging indices: thread loads float4 #tid + j*512 of the 2048-float4 tile
    // tile float4 i -> row i>>6, chunk i&63
    const int stride = gridDim.x * ROWS_PER_ITER;
    int base = blockIdx.x * ROWS_PER_ITER;

    // prologue: load first tile into regs
    float4 av[4], mv[4];
#pragma unroll
    for (int j = 0; j < 4; ++j) {
        int i = tid + j * GEMM_THREADS;
        int grow = base + (i >> 6);
        int cc = i & 63;
        if (grow < N) {
            av[j] = ((const float4*)(in + (size_t)grow * IN_F))[cc];
            mv[j] = ((const float4*)(mask + (size_t)grow * IN_F))[cc];
        } else {
            av[j] = make_float4(0.f, 0.f, 0.f, 0.f);
            mv[j] = make_float4(0.f, 0.f, 0.f, 0.f);
        }
    }

    for (; base < N; base += stride) {
        __syncthreads();  // previous compute done (protects rbuf)
        // write (in*mask) regs -> rbuf
        float4* rb4 = (float4*)rbuf;
#pragma unroll
        for (int j = 0; j < 4; ++j) {
            int i = tid + j * GEMM_THREADS;
            float4 p;
            p.x = av[j].x * mv[j].x; p.y = av[j].y * mv[j].y;
            p.z = av[j].z * mv[j].z; p.w = av[j].w * mv[j].w;
            rb4[i] = p;
        }
        __syncthreads();  // rbuf ready

        // prefetch next tile into regs (hides under k-loop)
        int nb = base + stride;
        if (nb < N) {
#pragma unroll
            for (int j = 0; j < 4; ++j) {
                int i = tid + j * GEMM_THREADS;
                int grow = nb + (i >> 6);
                int cc = i & 63;
                if (grow < N) {
                    av[j] = ((const float4*)(in + (size_t)grow * IN_F))[cc];
                    mv[j] = ((const float4*)(mask + (size_t)grow * IN_F))[cc];
                } else {
                    av[j] = make_float4(0.f, 0.f, 0.f, 0.f);
                    mv[j] = make_float4(0.f, 0.f, 0.f, 0.f);
                }
            }
        }

        // compute: 2 rows x 4 cols
        float4 acc0 = {0.f, 0.f, 0.f, 0.f};
        float4 acc1 = {0.f, 0.f, 0.f, 0.f};
        const float4* Wl4 = (const float4*)Wlds;   // [256][32] float4
        const float* r0 = rbuf[rp * 2];
        const float* r1 = rbuf[rp * 2 + 1];
#pragma unroll 8
        for (int k = 0; k < IN_F; ++k) {
            float4 w = Wl4[k * 32 + cg];
            float a0 = r0[k];
            float a1 = r1[k];
            acc0.x += w.x * a0; acc0.y += w.y * a0;
            acc0.z += w.z * a0; acc0.w += w.w * a0;
            acc1.x += w.x * a1; acc1.y += w.y * a1;
            acc1.z += w.z * a1; acc1.w += w.w * a1;
        }
        int gr0 = base + rp * 2, gr1 = gr0 + 1;
        if (gr0 < N) ((float4*)(x + (size_t)gr0 * OUT_F))[cg] = acc0;
        if (gr1 < N) ((float4*)(x + (size_t)gr1 * OUT_F))[cg] = acc1;
    }
}

// ---------------- CSR build ----------------
__global__ __launch_bounds__(256)
void count_kernel(const int* __restrict__ edge_row, int* __restrict__ count,
                  int E) {
    int e = blockIdx.x * blockDim.x + threadIdx.x;
    if (e < E) atomicAdd(&count[edge_row[e]], 1);
}

__global__ __launch_bounds__(256)
void chunk_sums_kernel(const int* __restrict__ count, int* __restrict__ partial,
                       int N) {
    __shared__ int s[256];
    int tid = threadIdx.x;
    int base = blockIdx.x * CHUNK + tid * 4;
    int sum = 0;
#pragma unroll
    for (int j = 0; j < 4; ++j) {
        int i = base + j;
        if (i < N) sum += count[i];
    }
    s[tid] = sum;
    __syncthreads();
    for (int d = 128; d > 0; d >>= 1) {
        if (tid < d) s[tid] += s[tid + d];
        __syncthreads();
    }
    if (tid == 0) partial[blockIdx.x] = s[0];
}

__global__ void scan_chunks_kernel(const int* __restrict__ partial,
                                   int* __restrict__ chunk_off, int nchunks) {
    if (threadIdx.x == 0 && blockIdx.x == 0) {
        int acc = 0;
        for (int i = 0; i < nchunks; ++i) {
            chunk_off[i] = acc;
            acc += partial[i];
        }
    }
}

__global__ __launch_bounds__(256)
void chunk_scan_apply_kernel(const int* __restrict__ count,
                             const int* __restrict__ chunk_off,
                             int* __restrict__ row_start,
                             int* __restrict__ cursor, int N, int E) {
    __shared__ int s[256];
    int tid = threadIdx.x;
    int base = blockIdx.x * CHUNK + tid * 4;
    int c[4];
    int tsum = 0;
#pragma unroll
    for (int j = 0; j < 4; ++j) {
        int i = base + j;
        c[j] = (i < N) ? count[i] : 0;
        tsum += c[j];
    }
    s[tid] = tsum;
    __syncthreads();
    for (int d = 1; d < 256; d <<= 1) {
        int v = (tid >= d) ? s[tid - d] : 0;
        __syncthreads();
        s[tid] += v;
        __syncthreads();
    }
    int pre = chunk_off[blockIdx.x] + s[tid] - tsum;
#pragma unroll
    for (int j = 0; j < 4; ++j) {
        int i = base + j;
        if (i < N) { row_start[i] = pre; cursor[i] = pre; }
        pre += c[j];
    }
    if (blockIdx.x == 0 && tid == 0) row_start[N] = E;
}

__global__ __launch_bounds__(256)
void csr_scatter_kernel(const int* __restrict__ edge_row,
                        const int* __restrict__ edge_col,
                        const float* __restrict__ adj_val,
                        int* __restrict__ cursor, int2* __restrict__ cv,
                        int E) {
    int e = blockIdx.x * blockDim.x + threadIdx.x;
    if (e >= E) return;
    int r = edge_row[e];
    int pos = atomicAdd(&cursor[r], 1);
    int2 p;
    p.x = edge_col[e];
    p.y = __float_as_int(adj_val[e]);
    cv[pos] = p;
}

// ---------------- per-node gather + accumulate + ReLU ----------------
__global__ __launch_bounds__(256)
void gather_accum_kernel(const float* __restrict__ x,
                         const int2* __restrict__ cv,
                         const int* __restrict__ row_start,
                         float* __restrict__ out, int N) {
    int g = (blockIdx.x * blockDim.x + threadIdx.x) >> 5;  // node
    int lane = threadIdx.x & 31;
    if (g >= N) return;
    int s = row_start[g];
    int e1 = row_start[g + 1];
    float4 acc = {0.f, 0.f, 0.f, 0.f};
    int e = s;
    // 2-way unrolled: independent loads pipeline
    for (; e + 1 < e1; e += 2) {
        int2 p0 = cv[e];
        int2 p1 = cv[e + 1];
        float v0 = __int_as_float(p0.y);
        float v1 = __int_as_float(p1.y);
        float4 x0 = ((const float4*)x)[(size_t)p0.x * 32 + lane];
        float4 x1 = ((const float4*)x)[(size_t)p1.x * 32 + lane];
        acc.x += v0 * x0.x; acc.y += v0 * x0.y;
        acc.z += v0 * x0.z; acc.w += v0 * x0.w;
        acc.x += v1 * x1.x; acc.y += v1 * x1.y;
        acc.z += v1 * x1.z; acc.w += v1 * x1.w;
    }
    if (e < e1) {
        int2 p = cv[e];
        float v = __int_as_float(p.y);
        float4 xv = ((const float4*)x)[(size_t)p.x * 32 + lane];
        acc.x += v * xv.x; acc.y += v * xv.y;
        acc.z += v * xv.z; acc.w += v * xv.w;
    }
    acc.x = fmaxf(acc.x, 0.f); acc.y = fmaxf(acc.y, 0.f);
    acc.z = fmaxf(acc.z, 0.f); acc.w = fmaxf(acc.w, 0.f);
    ((float4*)(out + (size_t)g * OUT_F))[lane] = acc;
}

static inline size_t align_up(size_t v, size_t a) { return (v + a - 1) & ~(a - 1); }

extern "C" void kernel_launch(void* const* d_in, const int* in_sizes, int n_in,
                              void* d_out, int out_size, void* d_ws, size_t ws_size,
                              hipStream_t stream) {
    const float* input     = (const float*)d_in[0];
    const float* weight    = (const float*)d_in[1];
    const float* adj_val   = (const float*)d_in[2];
    const float* drop_mask = (const float*)d_in[3];
    const int*   edge_row  = (const int*)d_in[4];
    const int*   edge_col  = (const int*)d_in[5];
    float* out = (float*)d_out;

    const int N = in_sizes[0] / IN_F;     // 100000
    const int E = in_sizes[2];            // 1600000
    const int nchunks = (N + CHUNK - 1) / CHUNK;

    // workspace layout
    char* ws = (char*)d_ws;
    size_t off = 0;
    float* x = (float*)(ws + off);           off = align_up(off + (size_t)N * OUT_F * 4, 256);
    int* count = (int*)(ws + off);           off = align_up(off + (size_t)N * 4, 256);
    int* row_start = (int*)(ws + off);       off = align_up(off + (size_t)(N + 1) * 4, 256);
    int* cursor = (int*)(ws + off);          off = align_up(off + (size_t)N * 4, 256);
    int* partial = (int*)(ws + off);         off = align_up(off + (size_t)nchunks * 4, 256);
    int* chunk_off = (int*)(ws + off);       off = align_up(off + (size_t)nchunks * 4, 256);
    int2* cv = (int2*)(ws + off);            off = align_up(off + (size_t)E * 8, 256);

    // Phase 1: fused dropout + GEMM
    gemm_dropout_kernel<<<256, GEMM_THREADS, 0, stream>>>(input, drop_mask,
                                                          weight, x, N);

    // Phase 2: CSR build
    hipMemsetAsync(count, 0, (size_t)N * 4, stream);
    count_kernel<<<(E + 255) / 256, 256, 0, stream>>>(edge_row, count, E);
    chunk_sums_kernel<<<nchunks, 256, 0, stream>>>(count, partial, N);
    scan_chunks_kernel<<<1, 64, 0, stream>>>(partial, chunk_off, nchunks);
    chunk_scan_apply_kernel<<<nchunks, 256, 0, stream>>>(count, chunk_off,
                                                         row_start, cursor, N, E);
    csr_scatter_kernel<<<(E + 255) / 256, 256, 0, stream>>>(edge_row, edge_col,
                                                            adj_val, cursor, cv, E);
    // Phase 3: gather + accumulate + ReLU
    gather_accum_kernel<<<(N * 32 + 255) / 256, 256, 0, stream>>>(x, cv,
                                                                  row_start, out, N);
}

// Round 4
// 355.942 us; speedup vs baseline: 8.2328x; 1.1049x over previous
//
#include <hip/hip_runtime.h>

#define IN_F 256
#define OUT_F 128
#define CHUNK 1024

typedef __attribute__((ext_vector_type(8))) short short8v;
typedef __attribute__((ext_vector_type(4))) float float4v;

__device__ inline unsigned short f2bf(float f) {
    unsigned u = __float_as_uint(f);
    u += 0x7fff + ((u >> 16) & 1);   // RNE
    return (unsigned short)(u >> 16);
}

// ---------------- Kernel A: x = (input*mask) @ W  via split-A bf16 MFMA ----
// 512 thr (8 waves). BM=32 rows/tile. LDS: Wt bf16 transposed 64KB + A hi/lo
// 32KB = 96KB. B-fragments live in registers for the whole kernel.
__global__ __launch_bounds__(512, 1)
void gemm_mfma_kernel(const float* __restrict__ in,
                      const float* __restrict__ mask,
                      const float* __restrict__ W,
                      float* __restrict__ x, int N) {
    __shared__ __align__(128) char lds[98304]; // Wt [0,65536) | A2 [65536,98304)
    char* Wt = lds;
    char* A2 = lds + 65536;
    const int tid  = threadIdx.x;
    const int lane = tid & 63;
    const int w    = tid >> 6;

    // ---- stage Wt: bf16, transposed (Wt[col][k]), XOR-swizzled, once ----
    {
        const float4* W4 = (const float4*)W;
        int c4 = tid & 31;            // float4 col group
        int k0 = (tid >> 5) * 16;     // 16 k's per thread
        for (int kk = 0; kk < 16; ++kk) {
            int k = k0 + kk;
            float4 wv = W4[k * 32 + c4];
            float vals[4] = {wv.x, wv.y, wv.z, wv.w};
#pragma unroll
            for (int j = 0; j < 4; ++j) {
                int c = c4 * 4 + j;
                int chunk = ((k * 2) & ~15) ^ ((c & 7) << 4);
                *(unsigned short*)(Wt + c * 512 + chunk + ((k * 2) & 15)) =
                    f2bf(vals[j]);
            }
        }
    }
    __syncthreads();

    // ---- B-fragments -> registers (held for whole kernel) ----
    const int rowg = w & 1;           // row-group 0/1 (16 rows each)
    const int colq = w >> 1;          // col-quarter 0..3 (32 cols each)
    const int l15  = lane & 15;
    const int q    = lane >> 4;       // 0..3
    short8v bfrag[2][8];
#pragma unroll
    for (int ct = 0; ct < 2; ++ct) {
#pragma unroll
        for (int s = 0; s < 8; ++s) {
            int col  = colq * 32 + ct * 16 + l15;
            int byte = col * 512 + ((s * 64 + q * 16) ^ ((col & 7) << 4));
            bfrag[ct][s] = *(const short8v*)(Wt + byte);
        }
    }

    // staging / A-read index precompute
    const int srow = tid >> 4;            // 0..31
    const int skc  = (tid & 15) * 16;     // 16 elems of k
    const int arow = rowg * 16 + l15;     // 0..31
    const int axr  = (arow & 7) << 4;
    const int sxr  = (srow & 7) << 4;

    const int ntiles = (N + 31) >> 5;     // 3125 (exact for N=100000)
    int tile = blockIdx.x;
    if (tile >= ntiles) return;

    const float4* in4 = (const float4*)in;
    const float4* mk4 = (const float4*)mask;

    // prologue: load first tile
    float4 pin[4], pmk[4];
    {
        int grow = tile * 32 + srow;
        size_t base = (size_t)grow * 64 + (skc >> 2);
#pragma unroll
        for (int j = 0; j < 4; ++j) {
            if (grow < N) { pin[j] = in4[base + j]; pmk[j] = mk4[base + j]; }
            else { pin[j] = make_float4(0.f,0.f,0.f,0.f); pmk[j] = make_float4(0.f,0.f,0.f,0.f); }
        }
    }

    for (; tile < ntiles; tile += gridDim.x) {
        __syncthreads();   // previous tile's MFMAs done with A2
        // ---- dropout-multiply, split to bf16 hi/lo, write swizzled LDS ----
        {
            float f[16];
#pragma unroll
            for (int j = 0; j < 4; ++j) {
                f[j*4+0] = pin[j].x * pmk[j].x;
                f[j*4+1] = pin[j].y * pmk[j].y;
                f[j*4+2] = pin[j].z * pmk[j].z;
                f[j*4+3] = pin[j].w * pmk[j].w;
            }
            short8v h0, h1, l0, l1;
#pragma unroll
            for (int j = 0; j < 8; ++j) {
                unsigned short hb = f2bf(f[j]);
                h0[j] = (short)hb;
                l0[j] = (short)f2bf(f[j] - __uint_as_float((unsigned)hb << 16));
                unsigned short hb2 = f2bf(f[8+j]);
                h1[j] = (short)hb2;
                l1[j] = (short)f2bf(f[8+j] - __uint_as_float((unsigned)hb2 << 16));
            }
            int b0 = srow * 512 + ((skc * 2) ^ sxr);
            int b1 = srow * 512 + (((skc * 2) + 16) ^ sxr);
            *(short8v*)(A2 + b0) = h0;
            *(short8v*)(A2 + b1) = h1;
            *(short8v*)(A2 + 16384 + b0) = l0;
            *(short8v*)(A2 + 16384 + b1) = l1;
        }
        __syncthreads();   // A ready

        // ---- prefetch next tile (hides under MFMA) ----
        int nt = tile + gridDim.x;
        if (nt < ntiles) {
            int grow = nt * 32 + srow;
            size_t base = (size_t)grow * 64 + (skc >> 2);
#pragma unroll
            for (int j = 0; j < 4; ++j) {
                if (grow < N) { pin[j] = in4[base + j]; pmk[j] = mk4[base + j]; }
                else { pin[j] = make_float4(0.f,0.f,0.f,0.f); pmk[j] = make_float4(0.f,0.f,0.f,0.f); }
            }
        }

        // ---- K-loop: 16 A-frag reads, 32 MFMA ----
        float4v acc0 = {0.f, 0.f, 0.f, 0.f};
        float4v acc1 = {0.f, 0.f, 0.f, 0.f};
#pragma unroll
        for (int p = 0; p < 2; ++p) {
#pragma unroll
            for (int s = 0; s < 8; ++s) {
                int byte = p * 16384 + arow * 512 + ((s * 64 + q * 16) ^ axr);
                short8v a = *(const short8v*)(A2 + byte);
                acc0 = __builtin_amdgcn_mfma_f32_16x16x32_bf16(a, bfrag[0][s], acc0, 0, 0, 0);
                acc1 = __builtin_amdgcn_mfma_f32_16x16x32_bf16(a, bfrag[1][s], acc1, 0, 0, 0);
            }
        }

        // ---- store C (D: col=lane&15, row=(lane>>4)*4+reg) ----
        int growb = tile * 32 + rowg * 16 + q * 4;
        int gcol  = colq * 32 + l15;
#pragma unroll
        for (int r = 0; r < 4; ++r) {
            int grow = growb + r;
            if (grow < N) {
                x[(size_t)grow * OUT_F + gcol]      = acc0[r];
                x[(size_t)grow * OUT_F + gcol + 16] = acc1[r];
            }
        }
    }
}

// ---------------- CSR build ----------------
__global__ __launch_bounds__(256)
void count_kernel(const int* __restrict__ edge_row, int* __restrict__ count,
                  int E) {
    int e = blockIdx.x * blockDim.x + threadIdx.x;
    if (e < E) atomicAdd(&count[edge_row[e]], 1);
}

__global__ __launch_bounds__(256)
void chunk_sums_kernel(const int* __restrict__ count, int* __restrict__ partial,
                       int N) {
    __shared__ int s[256];
    int tid = threadIdx.x;
    int base = blockIdx.x * CHUNK + tid * 4;
    int sum = 0;
#pragma unroll
    for (int j = 0; j < 4; ++j) {
        int i = base + j;
        if (i < N) sum += count[i];
    }
    s[tid] = sum;
    __syncthreads();
    for (int d = 128; d > 0; d >>= 1) {
        if (tid < d) s[tid] += s[tid + d];
        __syncthreads();
    }
    if (tid == 0) partial[blockIdx.x] = s[0];
}

__global__ void scan_chunks_kernel(const int* __restrict__ partial,
                                   int* __restrict__ chunk_off, int nchunks) {
    if (threadIdx.x == 0 && blockIdx.x == 0) {
        int acc = 0;
        for (int i = 0; i < nchunks; ++i) {
            chunk_off[i] = acc;
            acc += partial[i];
        }
    }
}

__global__ __launch_bounds__(256)
void chunk_scan_apply_kernel(const int* __restrict__ count,
                             const int* __restrict__ chunk_off,
                             int* __restrict__ row_start,
                             int* __restrict__ cursor, int N, int E) {
    __shared__ int s[256];
    int tid = threadIdx.x;
    int base = blockIdx.x * CHUNK + tid * 4;
    int c[4];
    int tsum = 0;
#pragma unroll
    for (int j = 0; j < 4; ++j) {
        int i = base + j;
        c[j] = (i < N) ? count[i] : 0;
        tsum += c[j];
    }
    s[tid] = tsum;
    __syncthreads();
    for (int d = 1; d < 256; d <<= 1) {
        int v = (tid >= d) ? s[tid - d] : 0;
        __syncthreads();
        s[tid] += v;
        __syncthreads();
    }
    int pre = chunk_off[blockIdx.x] + s[tid] - tsum;
#pragma unroll
    for (int j = 0; j < 4; ++j) {
        int i = base + j;
        if (i < N) { row_start[i] = pre; cursor[i] = pre; }
        pre += c[j];
    }
    if (blockIdx.x == 0 && tid == 0) row_start[N] = E;
}

__global__ __launch_bounds__(256)
void csr_scatter_kernel(const int* __restrict__ edge_row,
                        const int* __restrict__ edge_col,
                        const float* __restrict__ adj_val,
                        int* __restrict__ cursor, int2* __restrict__ cv,
                        int E) {
    int e = blockIdx.x * blockDim.x + threadIdx.x;
    if (e >= E) return;
    int r = edge_row[e];
    int pos = atomicAdd(&cursor[r], 1);
    int2 p;
    p.x = edge_col[e];
    p.y = __float_as_int(adj_val[e]);
    cv[pos] = p;
}

// ---------------- per-node gather + accumulate + ReLU ----------------
__global__ __launch_bounds__(256)
void gather_accum_kernel(const float* __restrict__ x,
                         const int2* __restrict__ cv,
                         const int* __restrict__ row_start,
                         float* __restrict__ out, int N) {
    int g = (blockIdx.x * blockDim.x + threadIdx.x) >> 5;  // node
    int lane = threadIdx.x & 31;
    if (g >= N) return;
    int s = row_start[g];
    int e1 = row_start[g + 1];
    float4 acc = {0.f, 0.f, 0.f, 0.f};
    int e = s;
    for (; e + 1 < e1; e += 2) {
        int2 p0 = cv[e];
        int2 p1 = cv[e + 1];
        float v0 = __int_as_float(p0.y);
        float v1 = __int_as_float(p1.y);
        float4 x0 = ((const float4*)x)[(size_t)p0.x * 32 + lane];
        float4 x1 = ((const float4*)x)[(size_t)p1.x * 32 + lane];
        acc.x += v0 * x0.x; acc.y += v0 * x0.y;
        acc.z += v0 * x0.z; acc.w += v0 * x0.w;
        acc.x += v1 * x1.x; acc.y += v1 * x1.y;
        acc.z += v1 * x1.z; acc.w += v1 * x1.w;
    }
    if (e < e1) {
        int2 p = cv[e];
        float v = __int_as_float(p.y);
        float4 xv = ((const float4*)x)[(size_t)p.x * 32 + lane];
        acc.x += v * xv.x; acc.y += v * xv.y;
        acc.z += v * xv.z; acc.w += v * xv.w;
    }
    acc.x = fmaxf(acc.x, 0.f); acc.y = fmaxf(acc.y, 0.f);
    acc.z = fmaxf(acc.z, 0.f); acc.w = fmaxf(acc.w, 0.f);
    ((float4*)(out + (size_t)g * OUT_F))[lane] = acc;
}

static inline size_t align_up(size_t v, size_t a) { return (v + a - 1) & ~(a - 1); }

extern "C" void kernel_launch(void* const* d_in, const int* in_sizes, int n_in,
                              void* d_out, int out_size, void* d_ws, size_t ws_size,
                              hipStream_t stream) {
    const float* input     = (const float*)d_in[0];
    const float* weight    = (const float*)d_in[1];
    const float* adj_val   = (const float*)d_in[2];
    const float* drop_mask = (const float*)d_in[3];
    const int*   edge_row  = (const int*)d_in[4];
    const int*   edge_col  = (const int*)d_in[5];
    float* out = (float*)d_out;

    const int N = in_sizes[0] / IN_F;     // 100000
    const int E = in_sizes[2];            // 1600000
    const int nchunks = (N + CHUNK - 1) / CHUNK;

    // workspace layout
    char* ws = (char*)d_ws;
    size_t off = 0;
    float* x = (float*)(ws + off);           off = align_up(off + (size_t)N * OUT_F * 4, 256);
    int* count = (int*)(ws + off);           off = align_up(off + (size_t)N * 4, 256);
    int* row_start = (int*)(ws + off);       off = align_up(off + (size_t)(N + 1) * 4, 256);
    int* cursor = (int*)(ws + off);          off = align_up(off + (size_t)N * 4, 256);
    int* partial = (int*)(ws + off);         off = align_up(off + (size_t)nchunks * 4, 256);
    int* chunk_off = (int*)(ws + off);       off = align_up(off + (size_t)nchunks * 4, 256);
    int2* cv = (int2*)(ws + off);            off = align_up(off + (size_t)E * 8, 256);

    // Phase 1: fused dropout + GEMM (MFMA bf16 split-A)
    gemm_mfma_kernel<<<256, 512, 0, stream>>>(input, drop_mask, weight, x, N);

    // Phase 2: CSR build
    hipMemsetAsync(count, 0, (size_t)N * 4, stream);
    count_kernel<<<(E + 255) / 256, 256, 0, stream>>>(edge_row, count, E);
    chunk_sums_kernel<<<nchunks, 256, 0, stream>>>(count, partial, N);
    scan_chunks_kernel<<<1, 64, 0, stream>>>(partial, chunk_off, nchunks);
    chunk_scan_apply_kernel<<<nchunks, 256, 0, stream>>>(count, chunk_off,
                                                         row_start, cursor, N, E);
    csr_scatter_kernel<<<(E + 255) / 256, 256, 0, stream>>>(edge_row, edge_col,
                                                            adj_val, cursor, cv, E);
    // Phase 3: gather + accumulate + ReLU
    gather_accum_kernel<<<(N * 32 + 255) / 256, 256, 0, stream>>>(x, cv,
                                                                  row_start, out, N);
}

// Round 5
// 278.625 us; speedup vs baseline: 10.5173x; 1.2775x over previous
//
#include <hip/hip_runtime.h>

#define IN_F 256
#define OUT_F 128
#define CHUNK 1024
#define NREGIONS 8
#define EPB 1024   // edges per chunk-block in region-filtered kernels

typedef __attribute__((ext_vector_type(8))) short short8v;
typedef __attribute__((ext_vector_type(4))) float float4v;

__device__ inline unsigned short f2bf(float f) {
    unsigned u = __float_as_uint(f);
    u += 0x7fff + ((u >> 16) & 1);   // RNE
    return (unsigned short)(u >> 16);
}

// ---------------- Kernel A: x = (input*mask) @ W  via split-A bf16 MFMA ----
// 512 thr (8 waves). BM=32 rows/tile. LDS: Wt bf16 transposed 64KB + A hi/lo
// 32KB = 96KB. B-fragments live in registers. Output x stored as bf16.
__global__ __launch_bounds__(512, 1)
void gemm_mfma_kernel(const float* __restrict__ in,
                      const float* __restrict__ mask,
                      const float* __restrict__ W,
                      unsigned short* __restrict__ xb, int N) {
    __shared__ __align__(128) char lds[98304]; // Wt [0,65536) | A2 [65536,98304)
    char* Wt = lds;
    char* A2 = lds + 65536;
    const int tid  = threadIdx.x;
    const int lane = tid & 63;
    const int w    = tid >> 6;

    // ---- stage Wt: bf16, transposed (Wt[col][k]), XOR-swizzled, once ----
    {
        const float4* W4 = (const float4*)W;
        int c4 = tid & 31;            // float4 col group
        int k0 = (tid >> 5) * 16;     // 16 k's per thread
        for (int kk = 0; kk < 16; ++kk) {
            int k = k0 + kk;
            float4 wv = W4[k * 32 + c4];
            float vals[4] = {wv.x, wv.y, wv.z, wv.w};
#pragma unroll
            for (int j = 0; j < 4; ++j) {
                int c = c4 * 4 + j;
                int chunk = ((k * 2) & ~15) ^ ((c & 7) << 4);
                *(unsigned short*)(Wt + c * 512 + chunk + ((k * 2) & 15)) =
                    f2bf(vals[j]);
            }
        }
    }
    __syncthreads();

    // ---- B-fragments -> registers (held for whole kernel) ----
    const int rowg = w & 1;
    const int colq = w >> 1;
    const int l15  = lane & 15;
    const int q    = lane >> 4;
    short8v bfrag[2][8];
#pragma unroll
    for (int ct = 0; ct < 2; ++ct) {
#pragma unroll
        for (int s = 0; s < 8; ++s) {
            int col  = colq * 32 + ct * 16 + l15;
            int byte = col * 512 + ((s * 64 + q * 16) ^ ((col & 7) << 4));
            bfrag[ct][s] = *(const short8v*)(Wt + byte);
        }
    }

    const int srow = tid >> 4;
    const int skc  = (tid & 15) * 16;
    const int arow = rowg * 16 + l15;
    const int axr  = (arow & 7) << 4;
    const int sxr  = (srow & 7) << 4;

    const int ntiles = (N + 31) >> 5;
    int tile = blockIdx.x;
    if (tile >= ntiles) return;

    const float4* in4 = (const float4*)in;
    const float4* mk4 = (const float4*)mask;

    float4 pin[4], pmk[4];
    {
        int grow = tile * 32 + srow;
        size_t base = (size_t)grow * 64 + (skc >> 2);
#pragma unroll
        for (int j = 0; j < 4; ++j) {
            if (grow < N) { pin[j] = in4[base + j]; pmk[j] = mk4[base + j]; }
            else { pin[j] = make_float4(0.f,0.f,0.f,0.f); pmk[j] = make_float4(0.f,0.f,0.f,0.f); }
        }
    }

    for (; tile < ntiles; tile += gridDim.x) {
        __syncthreads();
        {
            float f[16];
#pragma unroll
            for (int j = 0; j < 4; ++j) {
                f[j*4+0] = pin[j].x * pmk[j].x;
                f[j*4+1] = pin[j].y * pmk[j].y;
                f[j*4+2] = pin[j].z * pmk[j].z;
                f[j*4+3] = pin[j].w * pmk[j].w;
            }
            short8v h0, h1, l0, l1;
#pragma unroll
            for (int j = 0; j < 8; ++j) {
                unsigned short hb = f2bf(f[j]);
                h0[j] = (short)hb;
                l0[j] = (short)f2bf(f[j] - __uint_as_float((unsigned)hb << 16));
                unsigned short hb2 = f2bf(f[8+j]);
                h1[j] = (short)hb2;
                l1[j] = (short)f2bf(f[8+j] - __uint_as_float((unsigned)hb2 << 16));
            }
            int b0 = srow * 512 + ((skc * 2) ^ sxr);
            int b1 = srow * 512 + (((skc * 2) + 16) ^ sxr);
            *(short8v*)(A2 + b0) = h0;
            *(short8v*)(A2 + b1) = h1;
            *(short8v*)(A2 + 16384 + b0) = l0;
            *(short8v*)(A2 + 16384 + b1) = l1;
        }
        __syncthreads();

        int nt = tile + gridDim.x;
        if (nt < ntiles) {
            int grow = nt * 32 + srow;
            size_t base = (size_t)grow * 64 + (skc >> 2);
#pragma unroll
            for (int j = 0; j < 4; ++j) {
                if (grow < N) { pin[j] = in4[base + j]; pmk[j] = mk4[base + j]; }
                else { pin[j] = make_float4(0.f,0.f,0.f,0.f); pmk[j] = make_float4(0.f,0.f,0.f,0.f); }
            }
        }

        float4v acc0 = {0.f, 0.f, 0.f, 0.f};
        float4v acc1 = {0.f, 0.f, 0.f, 0.f};
#pragma unroll
        for (int p = 0; p < 2; ++p) {
#pragma unroll
            for (int s = 0; s < 8; ++s) {
                int byte = p * 16384 + arow * 512 + ((s * 64 + q * 16) ^ axr);
                short8v a = *(const short8v*)(A2 + byte);
                acc0 = __builtin_amdgcn_mfma_f32_16x16x32_bf16(a, bfrag[0][s], acc0, 0, 0, 0);
                acc1 = __builtin_amdgcn_mfma_f32_16x16x32_bf16(a, bfrag[1][s], acc1, 0, 0, 0);
            }
        }

        int growb = tile * 32 + rowg * 16 + q * 4;
        int gcol  = colq * 32 + l15;
#pragma unroll
        for (int r = 0; r < 4; ++r) {
            int grow = growb + r;
            if (grow < N) {
                xb[(size_t)grow * OUT_F + gcol]      = f2bf(acc0[r]);
                xb[(size_t)grow * OUT_F + gcol + 16] = f2bf(acc1[r]);
            }
        }
    }
}

// ---------------- CSR build (XCD-region-partitioned) ----------------
// Grid = NREGIONS * ceil(E/EPB). Block b: edge chunk b>>3, row-region b&7.
// With blockIdx%8 -> XCD round-robin, each region's count/cursor/cv lines are
// touched by exactly one XCD's L2: atomics stay local, lines evict once.
__global__ __launch_bounds__(256)
void count_xcd_kernel(const int* __restrict__ edge_row, int* __restrict__ count,
                      int E, int rpr) {
    int region = blockIdx.x & (NREGIONS - 1);
    int chunk  = blockIdx.x >> 3;
    int r0 = region * rpr;
    int e0 = chunk * EPB + threadIdx.x;
#pragma unroll
    for (int j = 0; j < EPB / 256; ++j) {
        int e = e0 + j * 256;
        if (e < E) {
            int r = edge_row[e];
            if ((unsigned)(r - r0) < (unsigned)rpr) atomicAdd(&count[r], 1);
        }
    }
}

__global__ __launch_bounds__(256)
void chunk_sums_kernel(const int* __restrict__ count, int* __restrict__ partial,
                       int N) {
    __shared__ int s[256];
    int tid = threadIdx.x;
    int base = blockIdx.x * CHUNK + tid * 4;
    int sum = 0;
#pragma unroll
    for (int j = 0; j < 4; ++j) {
        int i = base + j;
        if (i < N) sum += count[i];
    }
    s[tid] = sum;
    __syncthreads();
    for (int d = 128; d > 0; d >>= 1) {
        if (tid < d) s[tid] += s[tid + d];
        __syncthreads();
    }
    if (tid == 0) partial[blockIdx.x] = s[0];
}

// parallel exclusive scan of partial[nchunks] (nchunks <= 256)
__global__ __launch_bounds__(256)
void scan_chunks_kernel(const int* __restrict__ partial,
                        int* __restrict__ chunk_off, int nchunks) {
    __shared__ int s[256];
    int tid = threadIdx.x;
    if (nchunks > 256) {          // fallback (not hit for N=100000)
        if (tid == 0) {
            int acc = 0;
            for (int i = 0; i < nchunks; ++i) { chunk_off[i] = acc; acc += partial[i]; }
        }
        return;
    }
    int v = (tid < nchunks) ? partial[tid] : 0;
    s[tid] = v;
    __syncthreads();
    for (int d = 1; d < 256; d <<= 1) {
        int t = (tid >= d) ? s[tid - d] : 0;
        __syncthreads();
        s[tid] += t;
        __syncthreads();
    }
    if (tid < nchunks) chunk_off[tid] = s[tid] - v;
}

__global__ __launch_bounds__(256)
void chunk_scan_apply_kernel(const int* __restrict__ count,
                             const int* __restrict__ chunk_off,
                             int* __restrict__ row_start,
                             int* __restrict__ cursor, int N, int E) {
    __shared__ int s[256];
    int tid = threadIdx.x;
    int base = blockIdx.x * CHUNK + tid * 4;
    int c[4];
    int tsum = 0;
#pragma unroll
    for (int j = 0; j < 4; ++j) {
        int i = base + j;
        c[j] = (i < N) ? count[i] : 0;
        tsum += c[j];
    }
    s[tid] = tsum;
    __syncthreads();
    for (int d = 1; d < 256; d <<= 1) {
        int v = (tid >= d) ? s[tid - d] : 0;
        __syncthreads();
        s[tid] += v;
        __syncthreads();
    }
    int pre = chunk_off[blockIdx.x] + s[tid] - tsum;
#pragma unroll
    for (int j = 0; j < 4; ++j) {
        int i = base + j;
        if (i < N) { row_start[i] = pre; cursor[i] = pre; }
        pre += c[j];
    }
    if (blockIdx.x == 0 && tid == 0) row_start[N] = E;
}

__global__ __launch_bounds__(256)
void csr_scatter_xcd_kernel(const int* __restrict__ edge_row,
                            const int* __restrict__ edge_col,
                            const float* __restrict__ adj_val,
                            int* __restrict__ cursor, int2* __restrict__ cv,
                            int E, int rpr) {
    int region = blockIdx.x & (NREGIONS - 1);
    int chunk  = blockIdx.x >> 3;
    int r0 = region * rpr;
    int e0 = chunk * EPB + threadIdx.x;
#pragma unroll
    for (int j = 0; j < EPB / 256; ++j) {
        int e = e0 + j * 256;
        if (e < E) {
            int r = edge_row[e];
            if ((unsigned)(r - r0) < (unsigned)rpr) {
                int pos = atomicAdd(&cursor[r], 1);
                int2 p;
                p.x = edge_col[e];
                p.y = __float_as_int(adj_val[e]);
                cv[pos] = p;
            }
        }
    }
}

// ---------------- per-node gather + accumulate + ReLU (bf16 x) ----------
// 16 lanes per node; each lane owns 8 features (16B bf16 granule).
__global__ __launch_bounds__(256)
void gather_accum_kernel(const unsigned short* __restrict__ xb,
                         const int2* __restrict__ cv,
                         const int* __restrict__ row_start,
                         float* __restrict__ out, int N) {
    int g = (blockIdx.x * blockDim.x + threadIdx.x) >> 4;  // node
    int lane = threadIdx.x & 15;
    if (g >= N) return;
    int s = row_start[g];
    int e1 = row_start[g + 1];
    float acc[8] = {0.f,0.f,0.f,0.f,0.f,0.f,0.f,0.f};
    const uint4* xq = (const uint4*)xb;   // row r granule: r*16 + lane
    int e = s;
    for (; e + 1 < e1; e += 2) {
        int2 p0 = cv[e];
        int2 p1 = cv[e + 1];
        uint4 a = xq[(size_t)p0.x * 16 + lane];
        uint4 b = xq[(size_t)p1.x * 16 + lane];
        float v0 = __int_as_float(p0.y);
        float v1 = __int_as_float(p1.y);
        acc[0] += v0 * __uint_as_float(a.x << 16);
        acc[1] += v0 * __uint_as_float(a.x & 0xffff0000u);
        acc[2] += v0 * __uint_as_float(a.y << 16);
        acc[3] += v0 * __uint_as_float(a.y & 0xffff0000u);
        acc[4] += v0 * __uint_as_float(a.z << 16);
        acc[5] += v0 * __uint_as_float(a.z & 0xffff0000u);
        acc[6] += v0 * __uint_as_float(a.w << 16);
        acc[7] += v0 * __uint_as_float(a.w & 0xffff0000u);
        acc[0] += v1 * __uint_as_float(b.x << 16);
        acc[1] += v1 * __uint_as_float(b.x & 0xffff0000u);
        acc[2] += v1 * __uint_as_float(b.y << 16);
        acc[3] += v1 * __uint_as_float(b.y & 0xffff0000u);
        acc[4] += v1 * __uint_as_float(b.z << 16);
        acc[5] += v1 * __uint_as_float(b.z & 0xffff0000u);
        acc[6] += v1 * __uint_as_float(b.w << 16);
        acc[7] += v1 * __uint_as_float(b.w & 0xffff0000u);
    }
    if (e < e1) {
        int2 p = cv[e];
        uint4 a = xq[(size_t)p.x * 16 + lane];
        float v = __int_as_float(p.y);
        acc[0] += v * __uint_as_float(a.x << 16);
        acc[1] += v * __uint_as_float(a.x & 0xffff0000u);
        acc[2] += v * __uint_as_float(a.y << 16);
        acc[3] += v * __uint_as_float(a.y & 0xffff0000u);
        acc[4] += v * __uint_as_float(a.z << 16);
        acc[5] += v * __uint_as_float(a.z & 0xffff0000u);
        acc[6] += v * __uint_as_float(a.w << 16);
        acc[7] += v * __uint_as_float(a.w & 0xffff0000u);
    }
    float4 o0, o1;
    o0.x = fmaxf(acc[0], 0.f); o0.y = fmaxf(acc[1], 0.f);
    o0.z = fmaxf(acc[2], 0.f); o0.w = fmaxf(acc[3], 0.f);
    o1.x = fmaxf(acc[4], 0.f); o1.y = fmaxf(acc[5], 0.f);
    o1.z = fmaxf(acc[6], 0.f); o1.w = fmaxf(acc[7], 0.f);
    float4* dst = (float4*)(out + (size_t)g * OUT_F + lane * 8);
    dst[0] = o0;
    dst[1] = o1;
}

static inline size_t align_up(size_t v, size_t a) { return (v + a - 1) & ~(a - 1); }

extern "C" void kernel_launch(void* const* d_in, const int* in_sizes, int n_in,
                              void* d_out, int out_size, void* d_ws, size_t ws_size,
                              hipStream_t stream) {
    const float* input     = (const float*)d_in[0];
    const float* weight    = (const float*)d_in[1];
    const float* adj_val   = (const float*)d_in[2];
    const float* drop_mask = (const float*)d_in[3];
    const int*   edge_row  = (const int*)d_in[4];
    const int*   edge_col  = (const int*)d_in[5];
    float* out = (float*)d_out;

    const int N = in_sizes[0] / IN_F;     // 100000
    const int E = in_sizes[2];            // 1600000
    const int nchunks = (N + CHUNK - 1) / CHUNK;
    const int rpr = (N + NREGIONS - 1) / NREGIONS;   // rows per region
    const int nebk = (E + EPB - 1) / EPB;            // edge chunk blocks

    // workspace layout
    char* ws = (char*)d_ws;
    size_t off = 0;
    unsigned short* xbf = (unsigned short*)(ws + off);
    off = align_up(off + (size_t)N * OUT_F * 2, 256);
    int* count = (int*)(ws + off);           off = align_up(off + (size_t)N * 4, 256);
    int* row_start = (int*)(ws + off);       off = align_up(off + (size_t)(N + 1) * 4, 256);
    int* cursor = (int*)(ws + off);          off = align_up(off + (size_t)N * 4, 256);
    int* partial = (int*)(ws + off);         off = align_up(off + (size_t)nchunks * 4, 256);
    int* chunk_off = (int*)(ws + off);       off = align_up(off + (size_t)nchunks * 4, 256);
    int2* cv = (int2*)(ws + off);            off = align_up(off + (size_t)E * 8, 256);

    // Phase 1: fused dropout + GEMM (MFMA bf16 split-A, bf16 x out)
    gemm_mfma_kernel<<<256, 512, 0, stream>>>(input, drop_mask, weight, xbf, N);

    // Phase 2: CSR build (XCD-region-partitioned)
    hipMemsetAsync(count, 0, (size_t)N * 4, stream);
    count_xcd_kernel<<<nebk * NREGIONS, 256, 0, stream>>>(edge_row, count, E, rpr);
    chunk_sums_kernel<<<nchunks, 256, 0, stream>>>(count, partial, N);
    scan_chunks_kernel<<<1, 256, 0, stream>>>(partial, chunk_off, nchunks);
    chunk_scan_apply_kernel<<<nchunks, 256, 0, stream>>>(count, chunk_off,
                                                         row_start, cursor, N, E);
    csr_scatter_xcd_kernel<<<nebk * NREGIONS, 256, 0, stream>>>(edge_row, edge_col,
                                                                adj_val, cursor, cv,
                                                                E, rpr);
    // Phase 3: gather + accumulate + ReLU
    gather_accum_kernel<<<(N * 16 + 255) / 256, 256, 0, stream>>>(xbf, cv,
                                                                  row_start, out, N);
}